// Round 5
// baseline (1274.705 us; speedup 1.0000x reference)
//
#include <hip/hip_runtime.h>
#include <hip/hip_bf16.h>
#include <stdint.h>

// PairEnergies GNN on MI355X — round 5.
// r4 bug found: edge-FFN hidden (31.46MB) overlaid t1 (15.73MB) and clobbered
// the normalized weights/hV/ma/xm at d_out+31.46MB. Fix: 4 FFN chunks of RT/4
// so hidden == t1's exact footprint. Everything else identical to r4.

typedef __bf16 bf16_t;
typedef __attribute__((ext_vector_type(8))) __bf16 bf16x8;
typedef __attribute__((ext_vector_type(4))) float f32x4;

#define B_    2
#define N_    1024
#define KN    30
#define H_    128
#define L_    3
#define ODIM_ 400
#define NK    (N_ * KN)        // 30720
#define RT    (B_ * N_ * KN)   // 61440 edge rows
#define BN_   (B_ * N_)        // 2048 node rows

__device__ __forceinline__ float wred(float v) {
#pragma unroll
  for (int off = 32; off > 0; off >>= 1) v += __shfl_xor(v, off, 64);
  return v;
}

// ================= dtype sniff + normalize =================
__global__ void flag_kernel(const uint32_t* __restrict__ xm_raw,
                            int* __restrict__ flag)
{
  if (threadIdx.x == 0 && blockIdx.x == 0)
    *flag = (xm_raw[0] == 0x3F803F80u) ? 1 : 0;   // 1 = inputs are bf16
}

__global__ __launch_bounds__(256) void convert_kernel(
    const void* __restrict__ src, bf16_t* __restrict__ dst, int n,
    const int* __restrict__ flag)
{
  int i = blockIdx.x * 256 + threadIdx.x;
  if (i >= n) return;
  if (*flag) dst[i] = ((const bf16_t*)src)[i];
  else       dst[i] = (bf16_t)(((const float*)src)[i]);
}

// ================= generic MFMA GEMM =================
// C[M,N] = act(A[M,K] @ W[K,N] + bias). BM=BN=64, BK=32, 4 waves 2x2,
// wave computes 2x2 of mfma_f32_16x16x32_bf16. M%64==0, K%32==0, N%8==0.
__global__ __launch_bounds__(256) void gemm_kernel(
    const bf16_t* __restrict__ A, const bf16_t* __restrict__ W,
    const bf16_t* __restrict__ bias, bf16_t* __restrict__ C,
    int M, int N, int K, int act)
{
  constexpr int LDS_S = 40;
  __shared__ __align__(16) bf16_t As[64 * LDS_S];  // [m][k]
  __shared__ __align__(16) bf16_t Bs[64 * LDS_S];  // [n][k]

  const int tid  = threadIdx.x;
  const int lane = tid & 63;
  const int wave = tid >> 6;
  const int wm = wave & 1, wn = wave >> 1;
  const int row0 = blockIdx.y * 64;
  const int col0 = blockIdx.x * 64;

  const int a_row = tid >> 2;          // 0..63
  const int a_col = (tid & 3) << 3;    // 0,8,16,24
  const int w_k   = tid >> 3;          // 0..31
  const int w_n   = (tid & 7) << 3;    // 0..56

  const int fm = lane & 15;
  const int fk = (lane >> 4) << 3;

  f32x4 acc[2][2] = {};

  for (int k0 = 0; k0 < K; k0 += 32) {
    uint4 av = *reinterpret_cast<const uint4*>(
        A + (size_t)(row0 + a_row) * K + (k0 + a_col));
    uint4 wv = make_uint4(0u, 0u, 0u, 0u);
    if (col0 + w_n < N)   // N%8==0: uint4 fully in or out
      wv = *reinterpret_cast<const uint4*>(
          W + (size_t)(k0 + w_k) * N + (col0 + w_n));
    __syncthreads();
    *reinterpret_cast<uint4*>(&As[a_row * LDS_S + a_col]) = av;
    union { uint4 v; bf16_t e[8]; } wu; wu.v = wv;
#pragma unroll
    for (int j = 0; j < 8; ++j)
      Bs[(w_n + j) * LDS_S + w_k] = wu.e[j];
    __syncthreads();
#pragma unroll
    for (int mi = 0; mi < 2; ++mi) {
      bf16x8 af = *reinterpret_cast<const bf16x8*>(
          &As[(wm * 32 + mi * 16 + fm) * LDS_S + fk]);
#pragma unroll
      for (int ni = 0; ni < 2; ++ni) {
        bf16x8 bfr = *reinterpret_cast<const bf16x8*>(
            &Bs[(wn * 32 + ni * 16 + fm) * LDS_S + fk]);
        acc[mi][ni] = __builtin_amdgcn_mfma_f32_16x16x32_bf16(af, bfr, acc[mi][ni], 0, 0, 0);
      }
    }
  }

#pragma unroll
  for (int ni = 0; ni < 2; ++ni) {
    int col = col0 + wn * 32 + ni * 16 + fm;
    if (col >= N) continue;
    float bv = (float)bias[col];
#pragma unroll
    for (int mi = 0; mi < 2; ++mi) {
#pragma unroll
      for (int r = 0; r < 4; ++r) {
        int row = row0 + wm * 32 + mi * 16 + ((lane >> 4) << 2) + r;
        float v = acc[mi][ni][r] + bv;
        if (act) v = fmaxf(v, 0.f);
        C[(size_t)row * N + col] = (bf16_t)v;
      }
    }
  }
}

// ================= fused-gather GEMM1 =================
// C[RT,128] = relu(Avirt[RT,384] @ W[384,128] + bias)
// Avirt row r: seg0=hV[b,n]; mode0: seg1=hV[b,E_idx[r]], seg2=hE[r]
//                            mode1: seg1=hE[r],          seg2=hV[b,E_idx[r]]
__global__ __launch_bounds__(256) void gemm1_kernel(
    const bf16_t* __restrict__ hV, const bf16_t* __restrict__ hE,
    const int* __restrict__ E_idx, const bf16_t* __restrict__ W,
    const bf16_t* __restrict__ bias, bf16_t* __restrict__ C, int mode)
{
  constexpr int LDS_S = 40;
  __shared__ __align__(16) bf16_t As[64 * LDS_S];
  __shared__ __align__(16) bf16_t Bs[64 * LDS_S];

  const int tid  = threadIdx.x;
  const int lane = tid & 63;
  const int wave = tid >> 6;
  const int wm = wave & 1, wn = wave >> 1;
  const int row0 = blockIdx.y * 64;
  const int col0 = blockIdx.x * 64;   // 0 or 64 (N=128)

  const int a_row = tid >> 2;
  const int a_col = (tid & 3) << 3;
  const int w_k   = tid >> 3;
  const int w_n   = (tid & 7) << 3;

  const int fm = lane & 15;
  const int fk = (lane >> 4) << 3;

  const int r = row0 + a_row;
  const int b = r / NK;
  const int n = (r / KN) % N_;
  const bf16_t* pSelf = hV + (size_t)(b * N_ + n) * H_;
  const bf16_t* pGat  = hV + (size_t)(b * N_ + E_idx[r]) * H_;
  const bf16_t* pE    = hE + (size_t)r * H_;
  const bf16_t* seg1 = mode ? pE : pGat;
  const bf16_t* seg2 = mode ? pGat : pE;

  f32x4 acc[2][2] = {};

#pragma unroll
  for (int t = 0; t < 12; ++t) {
    const int k0 = t * 32;
    const int seg = k0 >> 7;            // 0,1,2
    const int kin = (k0 & 127) + a_col;
    const bf16_t* src = (seg == 0) ? pSelf : ((seg == 1) ? seg1 : seg2);
    uint4 av = *reinterpret_cast<const uint4*>(src + kin);
    uint4 wv = *reinterpret_cast<const uint4*>(
        W + (size_t)(k0 + w_k) * H_ + (col0 + w_n));
    __syncthreads();
    *reinterpret_cast<uint4*>(&As[a_row * LDS_S + a_col]) = av;
    union { uint4 v; bf16_t e[8]; } wu; wu.v = wv;
#pragma unroll
    for (int j = 0; j < 8; ++j)
      Bs[(w_n + j) * LDS_S + w_k] = wu.e[j];
    __syncthreads();
#pragma unroll
    for (int mi = 0; mi < 2; ++mi) {
      bf16x8 af = *reinterpret_cast<const bf16x8*>(
          &As[(wm * 32 + mi * 16 + fm) * LDS_S + fk]);
#pragma unroll
      for (int ni = 0; ni < 2; ++ni) {
        bf16x8 bfr = *reinterpret_cast<const bf16x8*>(
            &Bs[(wn * 32 + ni * 16 + fm) * LDS_S + fk]);
        acc[mi][ni] = __builtin_amdgcn_mfma_f32_16x16x32_bf16(af, bfr, acc[mi][ni], 0, 0, 0);
      }
    }
  }

#pragma unroll
  for (int ni = 0; ni < 2; ++ni) {
    int col = col0 + wn * 32 + ni * 16 + fm;
    float bv = (float)bias[col];
#pragma unroll
    for (int mi = 0; mi < 2; ++mi) {
#pragma unroll
      for (int rr = 0; rr < 4; ++rr) {
        int row = row0 + wm * 32 + mi * 16 + ((lane >> 4) << 2) + rr;
        float v = fmaxf(acc[mi][ni][rr] + bv, 0.f);   // always relu
        C[(size_t)row * H_ + col] = (bf16_t)v;
      }
    }
  }
}

// ================= output head: fused inv-gather GEMM, dtype-aware store ===
// out[r,:] = hE[b*NK + inv[r], :] @ Wout[128,400] + bias   (M=RT,N=400,K=128)
__global__ __launch_bounds__(256) void gemm_out_kernel(
    const bf16_t* __restrict__ hE, const int* __restrict__ inv,
    const bf16_t* __restrict__ W, const bf16_t* __restrict__ bias,
    void* __restrict__ outv, const int* __restrict__ flag)
{
  constexpr int LDS_S = 40;
  __shared__ __align__(16) bf16_t As[64 * LDS_S];
  __shared__ __align__(16) bf16_t Bs[64 * LDS_S];

  const int fl = *flag;
  const int tid  = threadIdx.x;
  const int lane = tid & 63;
  const int wave = tid >> 6;
  const int wm = wave & 1, wn = wave >> 1;
  const int row0 = blockIdx.y * 64;
  const int col0 = blockIdx.x * 64;   // 0..384

  const int a_row = tid >> 2;
  const int a_col = (tid & 3) << 3;
  const int w_k   = tid >> 3;
  const int w_n   = (tid & 7) << 3;

  const int fm = lane & 15;
  const int fk = (lane >> 4) << 3;

  const int r = row0 + a_row;
  const int b = r / NK;
  const bf16_t* Arow = hE + (size_t)(b * NK + inv[r]) * H_;

  f32x4 acc[2][2] = {};

#pragma unroll
  for (int t = 0; t < 4; ++t) {
    const int k0 = t * 32;
    uint4 av = *reinterpret_cast<const uint4*>(Arow + k0 + a_col);
    uint4 wv = make_uint4(0u, 0u, 0u, 0u);
    if (col0 + w_n < ODIM_)
      wv = *reinterpret_cast<const uint4*>(
          W + (size_t)(k0 + w_k) * ODIM_ + (col0 + w_n));
    __syncthreads();
    *reinterpret_cast<uint4*>(&As[a_row * LDS_S + a_col]) = av;
    union { uint4 v; bf16_t e[8]; } wu; wu.v = wv;
#pragma unroll
    for (int j = 0; j < 8; ++j)
      Bs[(w_n + j) * LDS_S + w_k] = wu.e[j];
    __syncthreads();
#pragma unroll
    for (int mi = 0; mi < 2; ++mi) {
      bf16x8 af = *reinterpret_cast<const bf16x8*>(
          &As[(wm * 32 + mi * 16 + fm) * LDS_S + fk]);
#pragma unroll
      for (int ni = 0; ni < 2; ++ni) {
        bf16x8 bfr = *reinterpret_cast<const bf16x8*>(
            &Bs[(wn * 32 + ni * 16 + fm) * LDS_S + fk]);
        acc[mi][ni] = __builtin_amdgcn_mfma_f32_16x16x32_bf16(af, bfr, acc[mi][ni], 0, 0, 0);
      }
    }
  }

#pragma unroll
  for (int ni = 0; ni < 2; ++ni) {
    int col = col0 + wn * 32 + ni * 16 + fm;
    if (col >= ODIM_) continue;
    float bv = (float)bias[col];
#pragma unroll
    for (int mi = 0; mi < 2; ++mi) {
#pragma unroll
      for (int rr = 0; rr < 4; ++rr) {
        int row = row0 + wm * 32 + mi * 16 + ((lane >> 4) << 2) + rr;
        float v = acc[mi][ni][rr] + bv;
        size_t idx = (size_t)row * ODIM_ + col;
        if (fl) ((bf16_t*)outv)[idx] = (bf16_t)v;
        else    ((float*)outv)[idx]  = v;
      }
    }
  }
}

// ================= mask_attend (from normalized bf16 xm) =================
__global__ __launch_bounds__(256) void mask_kernel(
    const bf16_t* __restrict__ xm, const int* __restrict__ E_idx,
    float* __restrict__ ma)
{
  int r = blockIdx.x * 256 + threadIdx.x;
  if (r >= RT) return;
  int b = r / NK;
  int n = (r / KN) % N_;
  ma[r] = (float)xm[b * N_ + E_idx[r]] * (float)xm[b * N_ + n];
}

// ================= node aggregate + LN =================
__global__ __launch_bounds__(128) void node_agg_ln_kernel(
    const bf16_t* __restrict__ m3, const float* __restrict__ ma,
    bf16_t* __restrict__ hV)
{
  int bn = blockIdx.x;
  int c = threadIdx.x;
  const bf16_t* mrow = m3 + (size_t)bn * (KN * H_) + c;
  const float* mar = ma + (size_t)bn * KN;
  float s = 0.f;
#pragma unroll
  for (int k = 0; k < KN; ++k) s = fmaf((float)mrow[(size_t)k * H_], mar[k], s);
  float v = (float)hV[(size_t)bn * H_ + c] + s * (1.0f / 30.0f);

  __shared__ float red[4];
  float ss = wred(v), s2 = wred(v * v);
  int w = c >> 6, lane = c & 63;
  if (lane == 0) { red[w * 2] = ss; red[w * 2 + 1] = s2; }
  __syncthreads();
  float tot = red[0] + red[2], tot2 = red[1] + red[3];
  float mu = tot * (1.f / 128.f);
  float var = fmaxf(tot2 * (1.f / 128.f) - mu * mu, 0.f);
  float rstd = rsqrtf(var + 1e-5f);
  hV[(size_t)bn * H_ + c] = (bf16_t)((v - mu) * rstd);
}

// ================= node FFN + LN + mask =================
__global__ __launch_bounds__(128) void ffn_node_kernel(
    bf16_t* __restrict__ hV,
    const bf16_t* __restrict__ Wd1, const bf16_t* __restrict__ bd1,
    const bf16_t* __restrict__ Wd2, const bf16_t* __restrict__ bd2,
    const bf16_t* __restrict__ xm)
{
  int bn = blockIdx.x;
  int c = threadIdx.x;  // 0..127
  __shared__ float xs[128];
  __shared__ float hs[512];
  float xv = (float)hV[(size_t)bn * H_ + c];
  xs[c] = xv;
  __syncthreads();
#pragma unroll
  for (int g = 0; g < 4; ++g) {
    int j = g * 128 + c;
    float h = (float)bd1[j];
    for (int i = 0; i < 128; ++i) h = fmaf(xs[i], (float)Wd1[i * 512 + j], h);
    hs[j] = fmaxf(h, 0.f);
  }
  __syncthreads();
  float o = (float)bd2[c];
  for (int j = 0; j < 512; ++j) o = fmaf(hs[j], (float)Wd2[j * 128 + c], o);
  float v = xv + o;

  __shared__ float red[4];
  float ss = wred(v), s2 = wred(v * v);
  int w = c >> 6, lane = c & 63;
  if (lane == 0) { red[w * 2] = ss; red[w * 2 + 1] = s2; }
  __syncthreads();
  float tot = red[0] + red[2], tot2 = red[1] + red[3];
  float mu = tot * (1.f / 128.f);
  float var = fmaxf(tot2 * (1.f / 128.f) - mu * mu, 0.f);
  float rstd = rsqrtf(var + 1e-5f);
  float m = (float)xm[bn];
  hV[(size_t)bn * H_ + c] = (bf16_t)(((v - mu) * rstd) * m);
}

// ================= edge residual LN (wave/row) =================
__global__ __launch_bounds__(256) void edge_ln_kernel(
    const bf16_t* __restrict__ delta, bf16_t* __restrict__ hE,
    const float* __restrict__ ma, int usemask)
{
  int r = blockIdx.x * 4 + (threadIdx.x >> 6);
  int lane = threadIdx.x & 63;
  size_t base = (size_t)r * H_;
  float v0 = (float)hE[base + lane] + (float)delta[base + lane];
  float v1 = (float)hE[base + 64 + lane] + (float)delta[base + 64 + lane];
  float s = wred(v0 + v1);
  float s2 = wred(v0 * v0 + v1 * v1);
  float mu = s * (1.f / 128.f);
  float var = fmaxf(s2 * (1.f / 128.f) - mu * mu, 0.f);
  float rstd = rsqrtf(var + 1e-5f);
  float m = usemask ? ma[r] : 1.f;
  hE[base + lane]      = (bf16_t)((v0 - mu) * rstd * m);
  hE[base + 64 + lane] = (bf16_t)((v1 - mu) * rstd * m);
}

// ================= launch =================
extern "C" void kernel_launch(void* const* d_in, const int* in_sizes, int n_in,
                              void* d_out, int out_size, void* d_ws, size_t ws_size,
                              hipStream_t stream)
{
  const int* E_idx  = (const int*)d_in[2];
  const int* invmap = (const int*)d_in[3];

  // ---- ws (~15.84 MB): what the final out-GEMM reads while d_out is written
  char* ws = (char*)d_ws;
  size_t woff = 0;
  auto walloc = [&](size_t bytes) -> char* {
    char* p = ws + woff; woff += (bytes + 255) & ~(size_t)255; return p;
  };
  int*    flag    = (int*)walloc(4);
  bf16_t* WoutW_n = (bf16_t*)walloc((size_t)in_sizes[29] * 2);  // 100 KB
  bf16_t* Woutb_n = (bf16_t*)walloc((size_t)in_sizes[30] * 2);
  bf16_t* hE      = (bf16_t*)walloc((size_t)RT * H_ * 2);       // 15.73 MB

  // ---- d_out scratch (>=49.15MB; every byte rewritten by gemm_out) ----
  // [0,15.73) t0 | [15.73,31.46) t1 (also edge-FFN hidden, RT/4 chunks) |
  // [31.46,~34.8) wn[], hV, ma, xm
  char* ob = (char*)d_out;
  bf16_t* t0 = (bf16_t*)ob;
  bf16_t* t1 = (bf16_t*)(ob + (size_t)RT * H_ * 2);
  size_t ooff = (size_t)RT * H_ * 2 * 2;
  auto oalloc = [&](size_t bytes) -> char* {
    char* p = ob + ooff; ooff += (bytes + 255) & ~(size_t)255; return p;
  };
  bf16_t* hid = t1;  // [RT/4,512] = 15.73 MB = exactly t1's extent

  bf16_t* wn[29];
  for (int i = 5; i <= 28; ++i)
    wn[i] = (bf16_t*)oalloc((size_t)in_sizes[i] * 2);          // ~2.64 MB
  bf16_t* hV = (bf16_t*)oalloc((size_t)BN_ * H_ * 2);          // 0.52 MB
  float*  ma = (float*)oalloc((size_t)RT * 4);                 // 0.25 MB
  bf16_t* xm = (bf16_t*)oalloc((size_t)BN_ * 2);               // 4 KB

  auto conv = [&](int i, bf16_t* dst) {
    int n = in_sizes[i];
    convert_kernel<<<(n + 255) / 256, 256, 0, stream>>>(d_in[i], dst, n, flag);
  };
  auto gemm = [&](const bf16_t* A, const bf16_t* W, const bf16_t* bias, bf16_t* C,
                  int M, int N, int K, int act) {
    dim3 grid((N + 63) / 64, M / 64);
    gemm_kernel<<<grid, 256, 0, stream>>>(A, W, bias, C, M, N, K, act);
  };

  // ---- sniff dtype, normalize all float inputs to bf16 ----
  flag_kernel<<<1, 64, 0, stream>>>((const uint32_t*)d_in[4], flag);
  conv(4, xm);
  for (int i = 5; i <= 28; ++i) conv(i, wn[i]);
  conv(29, WoutW_n);
  conv(30, Woutb_n);
  conv(0, t1);   // h_V0 -> t1
  conv(1, t0);   // h_E0 -> t0

  mask_kernel<<<RT / 256, 256, 0, stream>>>(xm, E_idx, ma);
  gemm(t1, wn[5], wn[6], hV, BN_, H_, H_, 0);   // W_v embed
  gemm(t0, wn[7], wn[8], hE, RT, H_, H_, 0);    // W_e embed

  for (int l = 0; l < L_; ++l) {
    const size_t wo1 = (size_t)l * 384 * 128, wo2 = (size_t)l * 128 * 128;
    const size_t wod1 = (size_t)l * 128 * 512, wod2 = (size_t)l * 512 * 128;
    // ---- node update ----
    gemm1_kernel<<<dim3(2, RT / 64), 256, 0, stream>>>(
        hV, hE, E_idx, wn[9] + wo1, wn[10] + l * 128, t0, 0);
    gemm(t0, wn[11] + wo2, wn[12] + l * 128, t1, RT, 128, 128, 1);
    gemm(t1, wn[13] + wo2, wn[14] + l * 128, t0, RT, 128, 128, 0);
    node_agg_ln_kernel<<<BN_, 128, 0, stream>>>(t0, ma, hV);
    ffn_node_kernel<<<BN_, 128, 0, stream>>>(
        hV, wn[15] + wod1, wn[16] + l * 512, wn[17] + wod2, wn[18] + l * 128, xm);
    // ---- edge update ----
    gemm1_kernel<<<dim3(2, RT / 64), 256, 0, stream>>>(
        hV, hE, E_idx, wn[19] + wo1, wn[20] + l * 128, t0, 1);
    gemm(t0, wn[21] + wo2, wn[22] + l * 128, t1, RT, 128, 128, 1);
    gemm(t1, wn[23] + wo2, wn[24] + l * 128, t0, RT, 128, 128, 0);
    edge_ln_kernel<<<RT / 4, 256, 0, stream>>>(t0, hE, ma, 0);
    // edge FFN: 4 row-chunks of RT/4; hidden fits t1 exactly
    for (int c = 0; c < 4; ++c) {
      size_t roff = (size_t)c * (RT / 4);
      gemm(hE + roff * H_, wn[25] + wod1, wn[26] + l * 512, hid, RT / 4, 512, 128, 1);
      gemm(hid, wn[27] + wod2, wn[28] + l * 128, t0 + roff * H_, RT / 4, 128, 512, 0);
    }
    edge_ln_kernel<<<RT / 4, 256, 0, stream>>>(t0, hE, ma, 1);
  }

  // output head: fused merge_dups gather; reads only ws (hE, Wout_n, flag)
  gemm_out_kernel<<<dim3(7, RT / 64), 256, 0, stream>>>(
      hE, invmap, WoutW_n, Woutb_n, d_out, flag);
}

// Round 6
// 1095.669 us; speedup vs baseline: 1.1634x; 1.1634x over previous
//
#include <hip/hip_runtime.h>
#include <hip/hip_bf16.h>
#include <stdint.h>

// PairEnergies GNN on MI355X — round 6.
// New 128x128 MFMA GEMM core (global_load_lds + XOR-swizzled LDS), W1 split
// into node-level U/G + edge K=128 GEMM, LN fused into epilogues, weights
// pre-transposed by a single convert kernel. r5 small kernels kept.

typedef __bf16 bf16_t;
typedef __attribute__((ext_vector_type(8))) __bf16 bf16x8;
typedef __attribute__((ext_vector_type(4))) float f32x4;

#define B_    2
#define N_    1024
#define KN    30
#define H_    128
#define L_    3
#define ODIM_ 400
#define NK    (N_ * KN)        // 30720
#define RT    (B_ * N_ * KN)   // 61440
#define BN_   (B_ * N_)        // 2048

#define EPI_PLAIN 0
#define EPI_RELU  1
#define EPI_F32   2
#define EPI_ADDUG 3
#define EPI_LN    4
#define EPI_OUT   5

__device__ __forceinline__ float wred(float v) {
#pragma unroll
  for (int off = 32; off > 0; off >>= 1) v += __shfl_xor(v, off, 64);
  return v;
}

// async global->LDS, 16B per lane; lds base must be wave-uniform.
__device__ __forceinline__ void gld16(const bf16_t* g, bf16_t* l) {
  __builtin_amdgcn_global_load_lds(
      (__attribute__((address_space(1))) void*)(g),
      (__attribute__((address_space(3))) void*)(l), 16, 0, 0);
}

// ================= unified 128x128 MFMA GEMM =================
// C[M,N] = epi(A[M,K] @ Bt[N,ldb]^T(k-window koff) + bias)
// BM=BN=128, BK=64, 4 waves 2x2, wave = 4x4 frags of mfma_f32_16x16x32_bf16.
// LDS layout [row][64k] with granule-XOR swizzle (g' = g ^ (row&7)) so both
// the LDS-DMA staging (linear) and ds_read_b128 frag reads are conflict-free.
__global__ __launch_bounds__(256) void gk(
    const bf16_t* __restrict__ A, int lda,
    const bf16_t* __restrict__ Bt, int ldb, int koff,
    const bf16_t* __restrict__ bias,
    int N, int K, int epi,
    bf16_t* __restrict__ C,
    float* __restrict__ Cf, float* __restrict__ Cf1, int koff1,
    const float* __restrict__ U, const float* __restrict__ G,
    const int* __restrict__ E_idx,
    bf16_t* __restrict__ resid, const float* __restrict__ mvec, int row0g,
    const int* __restrict__ inv, const int* __restrict__ flag,
    void* __restrict__ outp)
{
  __shared__ __align__(16) bf16_t As[128 * 64];
  __shared__ __align__(16) bf16_t Bs[128 * 64];
  __shared__ float lnS[2][128];
  __shared__ float lnS2[2][128];

  float* CfD = Cf;
  if (epi == EPI_F32 && blockIdx.z == 1) { koff = koff1; bias = nullptr; CfD = Cf1; }

  const int tid = threadIdx.x;
  const int w = tid >> 6, l = tid & 63;
  const int wm = w & 1, wn = w >> 1;
  const int row0 = blockIdx.y * 128;
  const int col0 = blockIdx.x * 128;
  const int lr = l >> 3;                 // 0..7
  const int kg8 = ((l & 7) ^ lr) << 3;   // swizzled source granule (elems)

  const bf16_t* ap[4];
  const bf16_t* bp[4];
#pragma unroll
  for (int s = 0; s < 4; ++s) {
    int rA = row0 + w * 32 + s * 8 + lr;
    const bf16_t* abase;
    if (epi == EPI_OUT) {
      int bb = rA / NK;
      abase = A + (size_t)(bb * NK + inv[rA]) * lda;
    } else {
      abase = A + (size_t)rA * lda;
    }
    ap[s] = abase + kg8;
    int rB = col0 + w * 32 + s * 8 + lr;
    if (rB >= N) rB = N - 1;             // clamp; bad cols gated at store
    bp[s] = Bt + (size_t)rB * ldb + koff + kg8;
  }

  const int fm = l & 15, q = l >> 4, fx = fm & 7;
  f32x4 acc[4][4] = {};

  for (int kt = 0; kt < K; kt += 64) {
    __syncthreads();                     // prior frag reads done
#pragma unroll
    for (int s = 0; s < 4; ++s)
      gld16(ap[s] + kt, &As[w * 2048 + s * 512]);
#pragma unroll
    for (int s = 0; s < 4; ++s)
      gld16(bp[s] + kt, &Bs[w * 2048 + s * 512]);
    __syncthreads();                     // DMA drained (compiler vmcnt(0))
#pragma unroll
    for (int h = 0; h < 2; ++h) {
      bf16x8 af[4], bfv[4];
#pragma unroll
      for (int mi = 0; mi < 4; ++mi)
        af[mi] = *reinterpret_cast<const bf16x8*>(
            &As[(wm * 64 + mi * 16 + fm) * 64 + ((((h << 2) | q) ^ fx) << 3)]);
#pragma unroll
      for (int ni = 0; ni < 4; ++ni)
        bfv[ni] = *reinterpret_cast<const bf16x8*>(
            &Bs[(wn * 64 + ni * 16 + fm) * 64 + ((((h << 2) | q) ^ fx) << 3)]);
#pragma unroll
      for (int mi = 0; mi < 4; ++mi)
#pragma unroll
        for (int ni = 0; ni < 4; ++ni)
          acc[mi][ni] = __builtin_amdgcn_mfma_f32_16x16x32_bf16(
              af[mi], bfv[ni], acc[mi][ni], 0, 0, 0);
    }
  }

  // ---- epilogues (C/D layout: row = wm*64+mi*16+q*4+rr, col = wn*64+ni*16+fm)
  if (epi <= EPI_F32) {
#pragma unroll
    for (int ni = 0; ni < 4; ++ni) {
      int col = col0 + wn * 64 + ni * 16 + fm;
      if (col >= N) continue;
      float bv = bias ? (float)bias[col] : 0.f;
#pragma unroll
      for (int mi = 0; mi < 4; ++mi)
#pragma unroll
        for (int rr = 0; rr < 4; ++rr) {
          size_t rg = (size_t)(row0g + row0 + wm * 64 + mi * 16 + q * 4 + rr);
          float v = acc[mi][ni][rr] + bv;
          if (epi == EPI_RELU) v = fmaxf(v, 0.f);
          if (epi == EPI_F32) CfD[rg * N + col] = v;
          else                C[rg * N + col] = (bf16_t)v;
        }
    }
  } else if (epi == EPI_ADDUG) {
#pragma unroll
    for (int mi = 0; mi < 4; ++mi)
#pragma unroll
      for (int rr = 0; rr < 4; ++rr) {
        int rg = row0g + row0 + wm * 64 + mi * 16 + q * 4 + rr;
        const float* Urow = U + (size_t)(rg / KN) * 128;
        const float* Grow = G + (size_t)((rg / NK) * N_ + E_idx[rg]) * 128;
#pragma unroll
        for (int ni = 0; ni < 4; ++ni) {
          int col = wn * 64 + ni * 16 + fm;
          float bv = bias ? (float)bias[col] : 0.f;
          float v = fmaxf(acc[mi][ni][rr] + bv + Urow[col] + Grow[col], 0.f);
          C[(size_t)rg * 128 + col] = (bf16_t)v;
        }
      }
  } else if (epi == EPI_LN) {
    // resid = LN(resid + acc + bias) * (mvec? mvec[rg] : 1);  N must be 128
#pragma unroll
    for (int mi = 0; mi < 4; ++mi)
#pragma unroll
      for (int rr = 0; rr < 4; ++rr) {
        int lrow = wm * 64 + mi * 16 + q * 4 + rr;
        size_t rg = (size_t)(row0g + row0 + lrow);
        float s = 0.f, s2 = 0.f;
#pragma unroll
        for (int ni = 0; ni < 4; ++ni) {
          int col = wn * 64 + ni * 16 + fm;
          float v = acc[mi][ni][rr] + (bias ? (float)bias[col] : 0.f)
                    + (float)resid[rg * 128 + col];
          acc[mi][ni][rr] = v;
          s += v; s2 += v * v;
        }
#pragma unroll
        for (int d = 1; d < 16; d <<= 1) {
          s += __shfl_xor(s, d, 64); s2 += __shfl_xor(s2, d, 64);
        }
        if (fm == (mi * 4 + rr)) { lnS[wn][lrow] = s; lnS2[wn][lrow] = s2; }
      }
    __syncthreads();
#pragma unroll
    for (int mi = 0; mi < 4; ++mi)
#pragma unroll
      for (int rr = 0; rr < 4; ++rr) {
        int lrow = wm * 64 + mi * 16 + q * 4 + rr;
        size_t rg = (size_t)(row0g + row0 + lrow);
        float st = lnS[0][lrow] + lnS[1][lrow];
        float st2 = lnS2[0][lrow] + lnS2[1][lrow];
        float mu = st * (1.f / 128.f);
        float var = fmaxf(st2 * (1.f / 128.f) - mu * mu, 0.f);
        float rstd = rsqrtf(var + 1e-5f);
        float mk = mvec ? mvec[rg] : 1.f;
#pragma unroll
        for (int ni = 0; ni < 4; ++ni) {
          int col = wn * 64 + ni * 16 + fm;
          resid[rg * 128 + col] = (bf16_t)((acc[mi][ni][rr] - mu) * rstd * mk);
        }
      }
  } else {  // EPI_OUT
    const int fl = *flag;
#pragma unroll
    for (int ni = 0; ni < 4; ++ni) {
      int col = col0 + wn * 64 + ni * 16 + fm;
      if (col >= ODIM_) continue;
      float bv = bias ? (float)bias[col] : 0.f;
#pragma unroll
      for (int mi = 0; mi < 4; ++mi)
#pragma unroll
        for (int rr = 0; rr < 4; ++rr) {
          size_t rg = (size_t)(row0 + wm * 64 + mi * 16 + q * 4 + rr);
          float v = acc[mi][ni][rr] + bv;
          size_t idx = rg * ODIM_ + col;
          if (fl) ((bf16_t*)outp)[idx] = (bf16_t)v;
          else    ((float*)outp)[idx]  = v;
        }
    }
  }
}

// ================= dtype sniff =================
__global__ void flag_kernel(const uint32_t* __restrict__ xm_raw,
                            int* __restrict__ flag)
{
  if (threadIdx.x == 0 && blockIdx.x == 0)
    *flag = (xm_raw[0] == 0x3F803F80u) ? 1 : 0;   // 1 = inputs are bf16
}

// ================= fused convert (+ weight transpose) =================
struct ConvSeg { const void* src; void* dst; int n; int K; int N; };
struct ConvArgs { ConvSeg s[29]; };

__global__ __launch_bounds__(256) void conv_kernel(
    ConvArgs a, int nseg, int total8, const int* __restrict__ flag)
{
  int t = blockIdx.x * 256 + threadIdx.x;
  if (t >= total8) return;
  const int fl = *flag;
  int seg = 0, t8 = t;
  while (seg < nseg - 1 && t8 >= (a.s[seg].n >> 3)) { t8 -= a.s[seg].n >> 3; ++seg; }
  const ConvSeg sg = a.s[seg];
  const int e = t8 << 3;
  float vals[8];
  if (fl) {
    union { uint4 v; bf16_t b[8]; } u;
    u.v = *((const uint4*)sg.src + t8);
#pragma unroll
    for (int j = 0; j < 8; ++j) vals[j] = (float)u.b[j];
  } else {
    const float* sp = (const float*)sg.src + e;
#pragma unroll
    for (int j = 0; j < 8; ++j) vals[j] = sp[j];
  }
  if (sg.N == 0) {          // straight copy -> bf16
    union { uint4 v; bf16_t b[8]; } o;
#pragma unroll
    for (int j = 0; j < 8; ++j) o.b[j] = (bf16_t)vals[j];
    *((uint4*)sg.dst + t8) = o.v;
  } else {                  // per-layer transpose [K,N] -> [N,K]
    const int KN_ = sg.K * sg.N;
    const int lay = e / KN_;
    const int rem = e - lay * KN_;
    const int k = rem / sg.N;
    const int n0 = rem - k * sg.N;
    bf16_t* dp = (bf16_t*)sg.dst + (size_t)lay * KN_ + k;
#pragma unroll
    for (int j = 0; j < 8; ++j)
      dp[(size_t)(n0 + j) * sg.K] = (bf16_t)vals[j];
  }
}

// ================= mask_attend =================
__global__ __launch_bounds__(256) void mask_kernel(
    const bf16_t* __restrict__ xm, const int* __restrict__ E_idx,
    float* __restrict__ ma)
{
  int r = blockIdx.x * 256 + threadIdx.x;
  if (r >= RT) return;
  int b = r / NK;
  int n = (r / KN) % N_;
  ma[r] = (float)xm[b * N_ + E_idx[r]] * (float)xm[b * N_ + n];
}

// ================= node aggregate + LN =================
__global__ __launch_bounds__(128) void node_agg_ln_kernel(
    const bf16_t* __restrict__ m3, const float* __restrict__ ma,
    bf16_t* __restrict__ hV)
{
  int bn = blockIdx.x;
  int c = threadIdx.x;
  const bf16_t* mrow = m3 + (size_t)bn * (KN * H_) + c;
  const float* mar = ma + (size_t)bn * KN;
  float s = 0.f;
#pragma unroll
  for (int k = 0; k < KN; ++k) s = fmaf((float)mrow[(size_t)k * H_], mar[k], s);
  float v = (float)hV[(size_t)bn * H_ + c] + s * (1.0f / 30.0f);

  __shared__ float red[4];
  float ss = wred(v), s2 = wred(v * v);
  int w = c >> 6, lane = c & 63;
  if (lane == 0) { red[w * 2] = ss; red[w * 2 + 1] = s2; }
  __syncthreads();
  float tot = red[0] + red[2], tot2 = red[1] + red[3];
  float mu = tot * (1.f / 128.f);
  float var = fmaxf(tot2 * (1.f / 128.f) - mu * mu, 0.f);
  float rstd = rsqrtf(var + 1e-5f);
  hV[(size_t)bn * H_ + c] = (bf16_t)((v - mu) * rstd);
}

// ================= node FFN + LN + mask (transposed weights) =============
__global__ __launch_bounds__(128) void ffn_node_kernel(
    bf16_t* __restrict__ hV,
    const bf16_t* __restrict__ Wtd1, const bf16_t* __restrict__ bd1,
    const bf16_t* __restrict__ Wtd2, const bf16_t* __restrict__ bd2,
    const bf16_t* __restrict__ xm)
{
  int bn = blockIdx.x;
  int c = threadIdx.x;  // 0..127
  __shared__ float xs[128];
  __shared__ float hs[512];
  float xv = (float)hV[(size_t)bn * H_ + c];
  xs[c] = xv;
  __syncthreads();
#pragma unroll
  for (int g = 0; g < 4; ++g) {
    int j = g * 128 + c;
    const bf16_t* wr = Wtd1 + (size_t)j * 128;   // Wtd1: [512][128]
    float h = (float)bd1[j];
    for (int i = 0; i < 128; ++i) h = fmaf(xs[i], (float)wr[i], h);
    hs[j] = fmaxf(h, 0.f);
  }
  __syncthreads();
  const bf16_t* w2 = Wtd2 + (size_t)c * 512;     // Wtd2: [128][512]
  float o = (float)bd2[c];
  for (int j = 0; j < 512; ++j) o = fmaf(hs[j], (float)w2[j], o);
  float v = xv + o;

  __shared__ float red[4];
  float ss = wred(v), s2 = wred(v * v);
  int w = c >> 6, lane = c & 63;
  if (lane == 0) { red[w * 2] = ss; red[w * 2 + 1] = s2; }
  __syncthreads();
  float tot = red[0] + red[2], tot2 = red[1] + red[3];
  float mu = tot * (1.f / 128.f);
  float var = fmaxf(tot2 * (1.f / 128.f) - mu * mu, 0.f);
  float rstd = rsqrtf(var + 1e-5f);
  float m = (float)xm[bn];
  hV[(size_t)bn * H_ + c] = (bf16_t)(((v - mu) * rstd) * m);
}

// ================= launch =================
extern "C" void kernel_launch(void* const* d_in, const int* in_sizes, int n_in,
                              void* d_out, int out_size, void* d_ws, size_t ws_size,
                              hipStream_t stream)
{
  const int* E_idx  = (const int*)d_in[2];
  const int* invmap = (const int*)d_in[3];

  // ---- ws (~15.84 MB): read by final out-GEMM while d_out is being written
  char* ws = (char*)d_ws;
  size_t woff = 0;
  auto walloc = [&](size_t bytes) -> char* {
    char* p = ws + woff; woff += (bytes + 255) & ~(size_t)255; return p;
  };
  int*    flag  = (int*)walloc(4);
  bf16_t* WtOut = (bf16_t*)walloc((size_t)51200 * 2);   // [400][128]
  bf16_t* outbc = (bf16_t*)walloc((size_t)400 * 2);
  bf16_t* hE    = (bf16_t*)walloc((size_t)RT * H_ * 2); // 15.73 MB

  // ---- d_out scratch (fully rewritten by the final out-GEMM) ----
  char* ob = (char*)d_out;
  bf16_t* t0 = (bf16_t*)ob;                              // 15.73 MB
  bf16_t* t1 = (bf16_t*)(ob + (size_t)RT * H_ * 2);      // 15.73 MB
  bf16_t* hid = t0;  // edge-FFN hidden [RT/2,512] spans t0+t1 (both dead then)
  size_t ooff = (size_t)RT * H_ * 2 * 2;
  auto oalloc = [&](size_t bytes) -> char* {
    char* p = ob + ooff; ooff += (bytes + 255) & ~(size_t)255; return p;
  };
  bf16_t* WtV  = (bf16_t*)oalloc(16384 * 2);
  bf16_t* bvc  = (bf16_t*)oalloc(128 * 2);
  bf16_t* WtE  = (bf16_t*)oalloc(16384 * 2);
  bf16_t* bec  = (bf16_t*)oalloc(128 * 2);
  bf16_t* Wtn1 = (bf16_t*)oalloc((size_t)147456 * 2);
  bf16_t* nb1c = (bf16_t*)oalloc(384 * 2);
  bf16_t* Wtn2 = (bf16_t*)oalloc((size_t)49152 * 2);
  bf16_t* nb2c = (bf16_t*)oalloc(384 * 2);
  bf16_t* Wtn3 = (bf16_t*)oalloc((size_t)49152 * 2);
  bf16_t* nb3c = (bf16_t*)oalloc(384 * 2);
  bf16_t* Wtnd1 = (bf16_t*)oalloc((size_t)196608 * 2);
  bf16_t* nbd1c = (bf16_t*)oalloc(1536 * 2);
  bf16_t* Wtnd2 = (bf16_t*)oalloc((size_t)196608 * 2);
  bf16_t* nbd2c = (bf16_t*)oalloc(384 * 2);
  bf16_t* Wte1 = (bf16_t*)oalloc((size_t)147456 * 2);
  bf16_t* eb1c = (bf16_t*)oalloc(384 * 2);
  bf16_t* Wte2 = (bf16_t*)oalloc((size_t)49152 * 2);
  bf16_t* eb2c = (bf16_t*)oalloc(384 * 2);
  bf16_t* Wte3 = (bf16_t*)oalloc((size_t)49152 * 2);
  bf16_t* eb3c = (bf16_t*)oalloc(384 * 2);
  bf16_t* Wted1 = (bf16_t*)oalloc((size_t)196608 * 2);
  bf16_t* ebd1c = (bf16_t*)oalloc(1536 * 2);
  bf16_t* Wted2 = (bf16_t*)oalloc((size_t)196608 * 2);
  bf16_t* ebd2c = (bf16_t*)oalloc(384 * 2);
  float*  Ubuf = (float*)oalloc((size_t)BN_ * 128 * 4);  // 1 MB
  float*  Gbuf = (float*)oalloc((size_t)BN_ * 128 * 4);  // 1 MB
  bf16_t* hV   = (bf16_t*)oalloc((size_t)BN_ * 128 * 2);
  float*  ma   = (float*)oalloc((size_t)RT * 4);
  bf16_t* xm   = (bf16_t*)oalloc((size_t)BN_ * 2);
  // ooff tops out ~37 MB < 49.15 MB

  // ---- convert/transpose segment table ----
  ConvArgs ca;
  struct D { int idx; void* dst; int K; int N; };
  const D dl[29] = {
    {0, t1, 0, 0}, {1, t0, 0, 0}, {4, xm, 0, 0},
    {5, WtV, 128, 128}, {6, bvc, 0, 0}, {7, WtE, 128, 128}, {8, bec, 0, 0},
    {9, Wtn1, 384, 128}, {10, nb1c, 0, 0}, {11, Wtn2, 128, 128}, {12, nb2c, 0, 0},
    {13, Wtn3, 128, 128}, {14, nb3c, 0, 0},
    {15, Wtnd1, 128, 512}, {16, nbd1c, 0, 0}, {17, Wtnd2, 512, 128}, {18, nbd2c, 0, 0},
    {19, Wte1, 384, 128}, {20, eb1c, 0, 0}, {21, Wte2, 128, 128}, {22, eb2c, 0, 0},
    {23, Wte3, 128, 128}, {24, eb3c, 0, 0},
    {25, Wted1, 128, 512}, {26, ebd1c, 0, 0}, {27, Wted2, 512, 128}, {28, ebd2c, 0, 0},
    {29, WtOut, 128, 400}, {30, outbc, 0, 0}
  };
  int total8 = 0;
  for (int i = 0; i < 29; ++i) {
    ca.s[i].src = d_in[dl[i].idx];
    ca.s[i].dst = dl[i].dst;
    ca.s[i].n   = in_sizes[dl[i].idx];
    ca.s[i].K   = dl[i].K;
    ca.s[i].N   = dl[i].N;
    total8 += ca.s[i].n >> 3;
  }

  auto g = [&](dim3 grid, const bf16_t* A, int lda, const bf16_t* Bt, int ldb,
               int koff, const bf16_t* bias, int N, int K, int epi,
               bf16_t* C, float* Cf, float* Cf1, int koff1,
               bf16_t* resid, const float* mvec, int row0g) {
    gk<<<grid, 256, 0, stream>>>(A, lda, Bt, ldb, koff, bias, N, K, epi,
        C, Cf, Cf1, koff1, Ubuf, Gbuf, E_idx, resid, mvec, row0g,
        invmap, flag, d_out);
  };
  const float* NOM = nullptr;

  flag_kernel<<<1, 64, 0, stream>>>((const uint32_t*)d_in[4], flag);
  conv_kernel<<<(total8 + 255) / 256, 256, 0, stream>>>(ca, 29, total8, flag);
  mask_kernel<<<RT / 256, 256, 0, stream>>>(xm, E_idx, ma);

  // embeds
  g(dim3(1, BN_ / 128), t1, 128, WtV, 128, 0, bvc, 128, 128, EPI_PLAIN,
    hV, nullptr, nullptr, 0, nullptr, NOM, 0);
  g(dim3(1, RT / 128), t0, 128, WtE, 128, 0, bec, 128, 128, EPI_PLAIN,
    hE, nullptr, nullptr, 0, nullptr, NOM, 0);

  for (int l = 0; l < L_; ++l) {
    const bf16_t* W1n = Wtn1 + (size_t)l * 49152;
    const bf16_t* W2n = Wtn2 + (size_t)l * 16384;
    const bf16_t* W3n = Wtn3 + (size_t)l * 16384;
    const bf16_t* W1e = Wte1 + (size_t)l * 49152;
    const bf16_t* W2e = Wte2 + (size_t)l * 16384;
    const bf16_t* W3e = Wte3 + (size_t)l * 16384;
    // ---- node update ----
    g(dim3(1, BN_ / 128, 2), hV, 128, W1n, 384, 0, nb1c + l * 128, 128, 128,
      EPI_F32, nullptr, Ubuf, Gbuf, 128, nullptr, NOM, 0);
    g(dim3(1, RT / 128), hE, 128, W1n, 384, 256, nullptr, 128, 128, EPI_ADDUG,
      t0, nullptr, nullptr, 0, nullptr, NOM, 0);
    g(dim3(1, RT / 128), t0, 128, W2n, 128, 0, nb2c + l * 128, 128, 128, EPI_RELU,
      t1, nullptr, nullptr, 0, nullptr, NOM, 0);
    g(dim3(1, RT / 128), t1, 128, W3n, 128, 0, nb3c + l * 128, 128, 128, EPI_PLAIN,
      t0, nullptr, nullptr, 0, nullptr, NOM, 0);
    node_agg_ln_kernel<<<BN_, 128, 0, stream>>>(t0, ma, hV);
    ffn_node_kernel<<<BN_, 128, 0, stream>>>(
        hV, Wtnd1 + (size_t)l * 65536, nbd1c + l * 512,
        Wtnd2 + (size_t)l * 65536, nbd2c + l * 128, xm);
    // ---- edge update ----
    g(dim3(1, BN_ / 128, 2), hV, 128, W1e, 384, 0, eb1c + l * 128, 128, 128,
      EPI_F32, nullptr, Ubuf, Gbuf, 256, nullptr, NOM, 0);
    g(dim3(1, RT / 128), hE, 128, W1e, 384, 128, nullptr, 128, 128, EPI_ADDUG,
      t0, nullptr, nullptr, 0, nullptr, NOM, 0);
    g(dim3(1, RT / 128), t0, 128, W2e, 128, 0, eb2c + l * 128, 128, 128, EPI_RELU,
      t1, nullptr, nullptr, 0, nullptr, NOM, 0);
    g(dim3(1, RT / 128), t1, 128, W3e, 128, 0, eb3c + l * 128, 128, 128, EPI_LN,
      nullptr, nullptr, nullptr, 0, hE, NOM, 0);
    // edge FFN, 2 row-chunks of RT/2; hidden spans t0+t1
    for (int c = 0; c < 2; ++c) {
      int roff = c * (RT / 2);
      g(dim3(4, (RT / 2) / 128), hE + (size_t)roff * 128, 128,
        Wted1 + (size_t)l * 65536, 128, 0, ebd1c + l * 512, 512, 128, EPI_RELU,
        hid, nullptr, nullptr, 0, nullptr, NOM, 0);
      g(dim3(1, (RT / 2) / 128), hid, 512,
        Wted2 + (size_t)l * 65536, 512, 0, ebd2c + l * 128, 128, 512, EPI_LN,
        nullptr, nullptr, nullptr, 0, hE, ma, roff);
    }
  }

  // output head: fused merge_dups gather, dtype-aware store
  g(dim3(4, RT / 128), hE, 128, WtOut, 128, 0, outbc, ODIM_, 128, EPI_OUT,
    nullptr, nullptr, nullptr, 0, nullptr, NOM, 0);
}